// Round 16
// baseline (162.947 us; speedup 1.0000x reference)
//
#include <hip/hip_runtime.h>
#include <hip/hip_bf16.h>

#define S_LEN 4096
#define D_MODEL 512
#define DKV 64
#define B_N 4
#define STR 72    // K-tile LDS row stride (elems)
#define VSTR 136  // V/P LDS row stride (elems), 128 keys + pad

typedef __hip_bfloat16 bf16;
typedef __attribute__((ext_vector_type(8))) short short8;   // 8 bf16 (4 VGPRs)
typedef __attribute__((ext_vector_type(4))) float floatx4;  // MFMA C/D

#define MFMA(a, b, c) __builtin_amdgcn_mfma_f32_16x16x32_bf16(a, b, c, 0, 0, 0)

__device__ __forceinline__ float b2f(bf16 v) { return __bfloat162float(v); }

__device__ __forceinline__ unsigned short f2bits(float v) {
    union { bf16 h; unsigned short u; } cv;
    cv.h = __float2bfloat16(v);
    return cv.u;
}
__device__ __forceinline__ float bits2f(unsigned short u) {
    union { bf16 h; unsigned short u; } cv;
    cv.u = u;
    return b2f(cv.h);
}

// Split-K geometry: tile t (128 rows) has parts(t) = ceil((t+1)/2) parts,
// part p covers K-tiles {2p, min(2p+1, t)}. Slot offset within a batch:
// offT(t) = sum_{m<t} parts(m) = (t^2 + 2t + (t&1)) / 4.  Total 272/batch.
#define NSLOT_B 272
__device__ __forceinline__ int offT(int t) { return (t * t + 2 * t + (t & 1)) >> 2; }

// ---------------------------------------------------------------------------
// Kernel 1a (unified W prep + self-detect): each block detects dtype from x
// (64-lane scan, LDS broadcast); block 0 publishes global flag for qkv/proj.
// Blocks 0..11 -> Wq/Wk/Wv fragment-pack (16 cols each, hi/lo);
// blocks 12..43 -> Wo fragment-pack. Proven layouts from R6.
// ---------------------------------------------------------------------------
__global__ __launch_bounds__(512) void wprep_kernel(
    const void* __restrict__ x,
    const void* __restrict__ Wq, const void* __restrict__ bq,
    const void* __restrict__ Wk, const void* __restrict__ bk,
    const void* __restrict__ Wv, const void* __restrict__ bv,
    const void* __restrict__ Wo, const void* __restrict__ bo,
    bf16* __restrict__ Wfh, bf16* __restrict__ Wfl, float* __restrict__ ball,
    bf16* __restrict__ WoFh, bf16* __restrict__ WoFl, float* __restrict__ ball2,
    int* __restrict__ flag)
{
    __shared__ float xs[16][513];        // [col][k], padded
    __shared__ int sflag;
    const int blk = blockIdx.x;
    const int tid = threadIdx.x;
    union Pack8 { uint4 u; unsigned short s[8]; };

    if (tid < 64) {                      // self-detect (value-based; proven)
        const bf16* xb = (const bf16*)x;
        int bad = 0;
        for (int k = tid; k < 4096; k += 64) {
            float v = fabsf(b2f(xb[2 * k]));
            if (!(v < 64.f)) bad++;
        }
        #pragma unroll
        for (int off = 32; off >= 1; off >>= 1) bad += __shfl_xor(bad, off);
        if (tid == 0) {
            sflag = (bad > 100) ? 1 : 0;
            if (blk == 0) *flag = sflag;
        }
    }
    __syncthreads();
    const int f32 = sflag;

    if (blk < 12) {                      // ---- QKV W prep ----
        const int ct = blk;
        const int c0 = ct * 16;
        const int g = c0 >> 6;           // 0=Q 1=K 2=V
        const int cc0 = c0 & 63;
        const void* W    = (g == 0) ? Wq : (g == 1) ? Wk : Wv;
        const void* bias = (g == 0) ? bq : (g == 1) ? bk : bv;

        #pragma unroll
        for (int i = 0; i < 16; ++i) {
            const int idx = tid + 512 * i;   // 0..8191
            const int d = idx >> 4, j = idx & 15;
            const float v = f32 ? ((const float*)W)[(size_t)d * DKV + cc0 + j]
                                : b2f(((const bf16*)W)[(size_t)d * DKV + cc0 + j]);
            xs[j][d] = v;
        }
        __syncthreads();

        #pragma unroll
        for (int rep = 0; rep < 2; ++rep) {
            const int f = tid + rep * 512;   // fragment id: kt*64 + lane
            const int kt = f >> 6, lane = f & 63;
            const int quad = lane >> 4, l15 = lane & 15;
            Pack8 ph, pl;
            #pragma unroll
            for (int j = 0; j < 8; ++j) {
                const float v = xs[l15][kt * 32 + quad * 8 + j];
                const unsigned short hb = f2bits(v);
                ph.s[j] = hb;
                pl.s[j] = f2bits(v - bits2f(hb));
            }
            const size_t o = (((size_t)ct * 16 + kt) * 64 + lane) * 8;
            *(uint4*)&Wfh[o] = ph.u;
            *(uint4*)&Wfl[o] = pl.u;
        }
        if (tid < 16)
            ball[c0 + tid] = f32 ? ((const float*)bias)[cc0 + tid]
                                 : b2f(((const bf16*)bias)[cc0 + tid]);
    } else {                             // ---- Wo prep ----
        const int ctile = blk - 12;      // 0..31
        const int c0 = ctile * 16;

        #pragma unroll
        for (int rep = 0; rep < 2; ++rep) {
            const int idx = tid + rep * 512; // 0..1023
            const int d = idx >> 4, j = idx & 15;
            const float v = f32 ? ((const float*)Wo)[(size_t)d * D_MODEL + c0 + j]
                                : b2f(((const bf16*)Wo)[(size_t)d * D_MODEL + c0 + j]);
            xs[j][d] = v;
        }
        __syncthreads();

        if (tid < 128) {
            const int kc = tid >> 6, lane = tid & 63;
            const int quad = lane >> 4, l15 = lane & 15;
            Pack8 ph, pl;
            #pragma unroll
            for (int j = 0; j < 8; ++j) {
                const float v = xs[l15][kc * 32 + quad * 8 + j];
                const unsigned short hb = f2bits(v);
                ph.s[j] = hb;
                pl.s[j] = f2bits(v - bits2f(hb));
            }
            const size_t o = (((size_t)ctile * 2 + kc) * 64 + lane) * 8;
            *(uint4*)&WoFh[o] = ph.u;
            *(uint4*)&WoFl[o] = pl.u;
        }
        if (tid < 16)
            ball2[c0 + tid] = f32 ? ((const float*)bo)[c0 + tid]
                                  : b2f(((const bf16*)bo)[c0 + tid]);
    }
}

// ---------------------------------------------------------------------------
// Kernel 1b (unified QKV projection): block-uniform branch on dtype.
// fp32: 3-term hi/lo split; bf16: single term. Proven R8-R14.
// ---------------------------------------------------------------------------
__global__ __launch_bounds__(512) void qkv_mfma(
    const void* __restrict__ x,
    const bf16* __restrict__ Wfh, const bf16* __restrict__ Wfl,
    const float* __restrict__ ball,
    bf16* __restrict__ Qb, bf16* __restrict__ Kb, bf16* __restrict__ Vt,
    const int* __restrict__ flag)
{
    __shared__ unsigned short hiA[32 * D_MODEL];   // 32 KB
    __shared__ unsigned short loA[32 * D_MODEL];   // 32 KB (unused in bf16 path)
    const int tid = threadIdx.x;
    const int rowBase = blockIdx.x * 32;
    const int f32 = *flag;

    union Pack8 { uint4 u; unsigned short s[8]; };
    if (f32) {
        const float* xr = (const float*)x + (size_t)rowBase * D_MODEL;
        #pragma unroll
        for (int i = 0; i < 4; ++i) {
            const int idx = tid + 512 * i;       // 2048 8-elem chunks
            const int r = idx >> 6;
            const int c0 = (idx & 63) << 3;
            const float4 v0 = *(const float4*)&xr[r * D_MODEL + c0];
            const float4 v1 = *(const float4*)&xr[r * D_MODEL + c0 + 4];
            const float vv[8] = {v0.x, v0.y, v0.z, v0.w, v1.x, v1.y, v1.z, v1.w};
            Pack8 ph, pl;
            #pragma unroll
            for (int j = 0; j < 8; ++j) {
                const unsigned short hb = f2bits(vv[j]);
                ph.s[j] = hb;
                pl.s[j] = f2bits(vv[j] - bits2f(hb));
            }
            const int boff = (c0 * 2) ^ ((r & 7) << 4);
            *(uint4*)((char*)hiA + r * 1024 + boff) = ph.u;
            *(uint4*)((char*)loA + r * 1024 + boff) = pl.u;
        }
    } else {
        const unsigned short* xr = (const unsigned short*)x + (size_t)rowBase * D_MODEL;
        #pragma unroll
        for (int i = 0; i < 4; ++i) {
            const int idx = tid + 512 * i;
            const int r = idx >> 6;
            const int c0 = (idx & 63) << 3;
            const uint4 hv = *(const uint4*)&xr[r * D_MODEL + c0];
            const int boff = (c0 * 2) ^ ((r & 7) << 4);
            *(uint4*)((char*)hiA + r * 1024 + boff) = hv;
        }
    }
    __syncthreads();

    const int lane = tid & 63;
    const int w    = tid >> 6;           // 0..7
    const int quad = lane >> 4;
    const int l15  = lane & 15;
    const int wr   = w & 1;              // row half (16 rows)
    const int wq   = w >> 1;             // col quarter (48 cols = 3 tiles)
    const int arow = wr * 16 + l15;
    const char* hib = (const char*)hiA + arow * 1024;
    const char* lob = (const char*)loA + arow * 1024;
    const int swz = (arow & 7) << 4;

    floatx4 acc[3];
    #pragma unroll
    for (int ct = 0; ct < 3; ++ct) acc[ct] = (floatx4){0.f, 0.f, 0.f, 0.f};

    if (f32) {
        for (int kt = 0; kt < 16; ++kt) {
            const int boff = (kt * 64 + quad * 16) ^ swz;
            const short8 ah = *(const short8*)(hib + boff);
            const short8 al = *(const short8*)(lob + boff);
            #pragma unroll
            for (int ct = 0; ct < 3; ++ct) {
                const size_t fo = (((size_t)(wq * 3 + ct) * 16 + kt) * 64 + lane) * 8;
                const short8 bh = *(const short8*)&Wfh[fo];
                const short8 bl = *(const short8*)&Wfl[fo];
                acc[ct] = MFMA(ah, bh, acc[ct]);
                acc[ct] = MFMA(ah, bl, acc[ct]);
                acc[ct] = MFMA(al, bh, acc[ct]);
            }
        }
    } else {
        for (int kt = 0; kt < 16; ++kt) {
            const int boff = (kt * 64 + quad * 16) ^ swz;
            const short8 ah = *(const short8*)(hib + boff);
            #pragma unroll
            for (int ct = 0; ct < 3; ++ct) {
                const size_t fo = (((size_t)(wq * 3 + ct) * 16 + kt) * 64 + lane) * 8;
                const short8 bh = *(const short8*)&Wfh[fo];
                acc[ct] = MFMA(ah, bh, acc[ct]);
            }
        }
    }

    #pragma unroll
    for (int ct = 0; ct < 3; ++ct) {
        const int gc = wq * 48 + ct * 16 + l15;
        const float bias = ball[gc];
        const float scale = (gc < 64) ? 0.18033688f : 1.0f;
        #pragma unroll
        for (int r = 0; r < 4; ++r) {
            const int gr = rowBase + wr * 16 + quad * 4 + r;
            const bf16 o = __float2bfloat16((acc[ct][r] + bias) * scale);
            if (gc < 64)       Qb[(size_t)gr * DKV + gc] = o;
            else if (gc < 128) Kb[(size_t)gr * DKV + (gc - 64)] = o;
            else {
                const int bb = gr >> 12, sidx = gr & (S_LEN - 1);
                Vt[((size_t)bb * DKV + (gc - 128)) * S_LEN + sidx] = o;
            }
        }
    }
}

// ---------------------------------------------------------------------------
// Kernel 2: MFMA flash attention v6 — UNIFORM-WORK split-K (proven R13/R14).
// Q fragments loaded directly from global (L3-hot). (m, l) emitted as one
// float2 per row (single 8 B store; proj loads pairs).
// ---------------------------------------------------------------------------
__global__ __launch_bounds__(512, 2) void attn_mfma(
    const bf16* __restrict__ Qg, const bf16* __restrict__ Kg,
    const bf16* __restrict__ Vtg, float* __restrict__ Op,
    float2* __restrict__ ML)
{
    const int bid = blockIdx.x;
    const int b = bid & 3;
    const int j = (NSLOT_B - 1) - (bid >> 2);       // 0..271, big tiles first
    int t = (int)(2.0f * sqrtf((float)j + 1.0f));
    if (t > 31) t = 31;
    while (offT(t) > j) --t;
    while (t < 31 && offT(t + 1) <= j) ++t;
    const int p = j - offT(t);
    const int kb0 = 2 * p;
    const int kb1 = min(2 * p + 1, t);
    const int slot = b * NSLOT_B + offT(t) + p;
    const int rowBase = t * 128;
    const int tid = threadIdx.x;
    const int lane = tid & 63;
    const int w  = tid >> 6;             // wave 0..7: rows w*16..w*16+16
    const int quad = lane >> 4;
    const int l15  = lane & 15;

    __shared__ bf16 Kl[128 * STR];       // [key][dim]     18.0 KB
    __shared__ bf16 Vl[64 * VSTR];       // [vdim][key]    17.0 KB
    __shared__ bf16 Pl[128 * VSTR];      // [row][key]     34.0 KB
    // total 69 KB -> 2 blocks/CU

    const bf16* Qb = Qg + ((size_t)b * S_LEN + rowBase) * DKV;
    const bf16* Kb = Kg + (size_t)b * S_LEN * DKV;
    const bf16* Vb = Vtg + (size_t)b * DKV * S_LEN;

    // Q fragments straight from global (no LDS staging, no barrier)
    short8 qf0, qf1;
    {
        const bf16* qrow = Qb + (size_t)(w * 16 + l15) * DKV + quad * 8;
        qf0 = *(const short8*)qrow;
        qf1 = *(const short8*)(qrow + 32);
    }

    const short s1b = (short)0x3F80;     // bf16 1.0
    const short8 ones = {s1b, s1b, s1b, s1b, s1b, s1b, s1b, s1b};

    floatx4 acc[4];
    #pragma unroll
    for (int v = 0; v < 4; ++v) acc[v] = (floatx4){0.f, 0.f, 0.f, 0.f};
    floatx4 accl = {0.f, 0.f, 0.f, 0.f};
    float m_run[4];
    #pragma unroll
    for (int r = 0; r < 4; ++r) m_run[r] = -1e30f;

    const int kk = tid >> 2, dk = (tid & 3) * 16;   // K staging: 4 thr/row
    const int vd = tid >> 3, vk = (tid & 7) * 16;   // V staging: 8 thr/row

    uint4 kr0, kr1, vr0, vr1;
    {
        const uint4* ks = (const uint4*)&Kb[((size_t)(kb0 * 128 + kk)) * DKV + dk];
        kr0 = ks[0]; kr1 = ks[1];
        const uint4* vs = (const uint4*)&Vb[(size_t)vd * S_LEN + kb0 * 128 + vk];
        vr0 = vs[0]; vr1 = vs[1];
    }

    for (int kb = kb0; kb <= kb1; ++kb) {
        __syncthreads();                 // all waves done reading Kl/Vl
        {
            uint4* kd = (uint4*)&Kl[kk * STR + dk];
            kd[0] = kr0; kd[1] = kr1;
            uint4* vdst = (uint4*)&Vl[vd * VSTR + vk];
            vdst[0] = vr0; vdst[1] = vr1;
        }
        __syncthreads();                 // staging visible
        if (kb + 1 <= kb1) {             // prefetch next tile under compute
            const uint4* ks = (const uint4*)&Kb[((size_t)((kb + 1) * 128 + kk)) * DKV + dk];
            kr0 = ks[0]; kr1 = ks[1];
            const uint4* vs = (const uint4*)&Vb[(size_t)vd * S_LEN + (kb + 1) * 128 + vk];
            vr0 = vs[0]; vr1 = vs[1];
        }

        // S = Q K^T (Q pre-scaled): eight 16x16 key-tiles per wave
        floatx4 s[8];
        #pragma unroll
        for (int jt = 0; jt < 8; ++jt) s[jt] = (floatx4){0.f, 0.f, 0.f, 0.f};
        {
            const int qk = quad * 8;
            #pragma unroll
            for (int jt = 0; jt < 8; ++jt) {
                const int kc = (jt * 16 + l15) * STR + qk;
                const short8 ba = *(const short8*)&Kl[kc];
                const short8 bb = *(const short8*)&Kl[kc + 32];
                s[jt] = MFMA(qf0, ba, s[jt]);
                s[jt] = MFMA(qf1, bb, s[jt]);
            }
        }
        if (kb == t) {                   // causal mask, uniform branch
            const int rowg = rowBase + w * 16 + quad * 4;
            #pragma unroll
            for (int jt = 0; jt < 8; ++jt) {
                const int kg = kb * 128 + jt * 16 + l15;
                #pragma unroll
                for (int r = 0; r < 4; ++r)
                    if (kg > rowg + r) s[jt][r] = -1e30f;
            }
        }
        // wave-private row max: in-thread tree + 16-lane butterfly
        float m4[4];
        #pragma unroll
        for (int r = 0; r < 4; ++r) {
            float mm = s[0][r];
            #pragma unroll
            for (int jt = 1; jt < 8; ++jt) mm = fmaxf(mm, s[jt][r]);
            m4[r] = mm;
        }
        #pragma unroll
        for (int off = 1; off < 16; off <<= 1) {
            #pragma unroll
            for (int r = 0; r < 4; ++r) m4[r] = fmaxf(m4[r], __shfl_xor(m4[r], off));
        }
        float alpha[4];
        #pragma unroll
        for (int r = 0; r < 4; ++r) {
            const float mnew = fmaxf(m_run[r], m4[r]);
            alpha[r] = exp2f(m_run[r] - mnew);   // -1e30 first iter -> 0
            m_run[r] = mnew;
        }
        // P = exp2(S - m); rescale accumulators; write P to wave-private rows
        #pragma unroll
        for (int r = 0; r < 4; ++r) {
            accl[r] *= alpha[r];
            #pragma unroll
            for (int v = 0; v < 4; ++v) acc[v][r] *= alpha[r];
            const int poff = (w * 16 + quad * 4 + r) * VSTR + l15;
            #pragma unroll
            for (int jt = 0; jt < 8; ++jt) {
                const float pp = exp2f(s[jt][r] - m_run[r]);
                Pl[poff + jt * 16] = __float2bfloat16(pp);
            }
        }
        // same-wave LDS RAW: drain writes; "memory" clobber orders the ds_reads
        asm volatile("s_waitcnt lgkmcnt(0)" ::: "memory");

        // O += P V (and l += P . 1 via constant ones B-frag)
        {
            const int pk = quad * 8;
            const int prow = (w * 16 + l15) * VSTR;
            short8 pa[4];
            #pragma unroll
            for (int c = 0; c < 4; ++c)
                pa[c] = *(const short8*)&Pl[prow + pk + c * 32];
            #pragma unroll
            for (int c = 0; c < 4; ++c) accl = MFMA(pa[c], ones, accl);
            #pragma unroll
            for (int v = 0; v < 4; ++v) {
                const int vrow = (v * 16 + l15) * VSTR;
                #pragma unroll
                for (int c = 0; c < 4; ++c) {
                    const short8 vb = *(const short8*)&Vl[vrow + pk + c * 32];
                    acc[v] = MFMA(pa[c], vb, acc[v]);
                }
            }
        }
    }
    // epilogue: store unnormalized O + per-row (m, l) into this part's slot
    #pragma unroll
    for (int r = 0; r < 4; ++r) {
        const int lrow = w * 16 + quad * 4 + r;
        float* op = Op + ((size_t)slot * 128 + lrow) * DKV + l15;
        #pragma unroll
        for (int v = 0; v < 4; ++v) op[v * 16] = acc[v][r];
    }
    if (l15 == 0) {
        #pragma unroll
        for (int r = 0; r < 4; ++r) {
            const int lrow = w * 16 + quad * 4 + r;
            ML[slot * 128 + lrow] = make_float2(m_run[r], accl[r]);
        }
    }
}

// ---------------------------------------------------------------------------
// Kernel 3 (unified): fused variable-part split-K merge + output projection.
// SINGLE-PASS online merge (flash-style running rescale), 4-wide batched;
// (m, l) loaded as one float2 per part.
// ---------------------------------------------------------------------------
#define PSTR 72
__global__ __launch_bounds__(512) void proj_mfma(
    const float* __restrict__ Op, const float2* __restrict__ ML,
    const bf16* __restrict__ WoFh, const bf16* __restrict__ WoFl,
    const float* __restrict__ ball2, void* __restrict__ out,
    const int* __restrict__ flag)
{
    __shared__ unsigned short Ah[32 * PSTR], Al[32 * PSTR];
    const int tid = threadIdx.x;
    const int rowBase = blockIdx.x * 32;
    const int f32 = *flag;

    {   // fused merge: 4 floats per thread (rr = tid>>4, dd = (tid&15)*4)
        const int rr = tid >> 4, dd = (tid & 15) * 4;
        const int row = rowBase + rr;                // global row
        const int bb = row >> 12;
        const int sIdx = row & (S_LEN - 1);
        const int tt = sIdx >> 7;
        const int lrow = sIdx & 127;
        const int nparts = (tt + 2) >> 1;            // ceil((tt+1)/2)
        const int sbase = bb * NSLOT_B + offT(tt);

        float m = -1e30f, denom = 0.f;
        float oacc[4] = {0.f, 0.f, 0.f, 0.f};
        int i = 0;
        for (; i + 4 <= nparts; i += 4) {            // 4-wide independent loads
            const float2 a0 = ML[(sbase + i + 0) * 128 + lrow];
            const float2 a1 = ML[(sbase + i + 1) * 128 + lrow];
            const float2 a2 = ML[(sbase + i + 2) * 128 + lrow];
            const float2 a3 = ML[(sbase + i + 3) * 128 + lrow];
            const float4 v0 = *(const float4*)&Op[((size_t)(sbase + i + 0) * 128 + lrow) * DKV + dd];
            const float4 v1 = *(const float4*)&Op[((size_t)(sbase + i + 1) * 128 + lrow) * DKV + dd];
            const float4 v2 = *(const float4*)&Op[((size_t)(sbase + i + 2) * 128 + lrow) * DKV + dd];
            const float4 v3 = *(const float4*)&Op[((size_t)(sbase + i + 3) * 128 + lrow) * DKV + dd];
            const float gm = fmaxf(fmaxf(a0.x, a1.x), fmaxf(a2.x, a3.x));
            const float mnew = fmaxf(m, gm);
            const float sc = exp2f(m - mnew);        // m=-1e30 first group -> 0
            const float w0 = exp2f(a0.x - mnew), w1 = exp2f(a1.x - mnew);
            const float w2 = exp2f(a2.x - mnew), w3 = exp2f(a3.x - mnew);
            denom = denom * sc + a0.y * w0 + a1.y * w1 + a2.y * w2 + a3.y * w3;
            oacc[0] = oacc[0] * sc + v0.x * w0 + v1.x * w1 + v2.x * w2 + v3.x * w3;
            oacc[1] = oacc[1] * sc + v0.y * w0 + v1.y * w1 + v2.y * w2 + v3.y * w3;
            oacc[2] = oacc[2] * sc + v0.z * w0 + v1.z * w1 + v2.z * w2 + v3.z * w3;
            oacc[3] = oacc[3] * sc + v0.w * w0 + v1.w * w1 + v2.w * w2 + v3.w * w3;
            m = mnew;
        }
        for (; i < nparts; ++i) {                    // remainder (<=3 parts)
            const float2 a = ML[(sbase + i) * 128 + lrow];
            const float4 v = *(const float4*)&Op[((size_t)(sbase + i) * 128 + lrow) * DKV + dd];
            const float mnew = fmaxf(m, a.x);
            const float sc = exp2f(m - mnew);
            const float wi = exp2f(a.x - mnew);
            denom = denom * sc + a.y * wi;
            oacc[0] = oacc[0] * sc + v.x * wi;
            oacc[1] = oacc[1] * sc + v.y * wi;
            oacc[2] = oacc[2] * sc + v.z * wi;
            oacc[3] = oacc[3] * sc + v.w * wi;
            m = mnew;
        }
        const float inv = 1.0f / denom;
        union Pack4 { uint2 u; unsigned short s[4]; };
        Pack4 ph, pl;
        #pragma unroll
        for (int jj = 0; jj < 4; ++jj) {
            const float o = oacc[jj] * inv;
            ph.s[jj] = f2bits(o);
            pl.s[jj] = f2bits(o - bits2f(ph.s[jj]));
        }
        *(uint2*)&Ah[rr * PSTR + dd] = ph.u;
        *(uint2*)&Al[rr * PSTR + dd] = pl.u;
    }
    __syncthreads();

    const int lane = tid & 63;
    const int w    = tid >> 6;           // 0..7
    const int quad = lane >> 4;
    const int l15  = lane & 15;
    const int wr   = w & 1;
    const int wcq  = w >> 1;             // 0..3 col quarter (128 cols)

    const int aoff = (wr * 16 + l15) * PSTR + quad * 8;
    const short8 ah0 = *(const short8*)&Ah[aoff];
    const short8 ah1 = *(const short8*)&Ah[aoff + 32];
    const short8 al0 = *(const short8*)&Al[aoff];
    const short8 al1 = *(const short8*)&Al[aoff + 32];

    floatx4 acc[8];
    #pragma unroll
    for (int ct = 0; ct < 8; ++ct) acc[ct] = (floatx4){0.f, 0.f, 0.f, 0.f};

    if (f32) {
        #pragma unroll
        for (int ct = 0; ct < 8; ++ct) {
            const int ctile = wcq * 8 + ct;
            const size_t o0 = (((size_t)ctile * 2 + 0) * 64 + lane) * 8;
            const size_t o1 = (((size_t)ctile * 2 + 1) * 64 + lane) * 8;
            const short8 bh0 = *(const short8*)&WoFh[o0];
            const short8 bh1 = *(const short8*)&WoFh[o1];
            const short8 bl0 = *(const short8*)&WoFl[o0];
            const short8 bl1 = *(const short8*)&WoFl[o1];
            acc[ct] = MFMA(ah0, bh0, acc[ct]);
            acc[ct] = MFMA(ah1, bh1, acc[ct]);
            acc[ct] = MFMA(ah0, bl0, acc[ct]);
            acc[ct] = MFMA(ah1, bl1, acc[ct]);
            acc[ct] = MFMA(al0, bh0, acc[ct]);
            acc[ct] = MFMA(al1, bh1, acc[ct]);
        }
        float* outf = (float*)out;
        #pragma unroll
        for (int ct = 0; ct < 8; ++ct) {
            const int col = wcq * 128 + ct * 16 + l15;
            const float bias = ball2[col];
            #pragma unroll
            for (int r = 0; r < 4; ++r) {
                const int row = rowBase + wr * 16 + quad * 4 + r;
                outf[(size_t)row * D_MODEL + col] = acc[ct][r] + bias;
            }
        }
    } else {
        #pragma unroll
        for (int ct = 0; ct < 8; ++ct) {
            const int ctile = wcq * 8 + ct;
            const size_t o0 = (((size_t)ctile * 2 + 0) * 64 + lane) * 8;
            const size_t o1 = (((size_t)ctile * 2 + 1) * 64 + lane) * 8;
            const short8 bh0 = *(const short8*)&WoFh[o0];
            const short8 bh1 = *(const short8*)&WoFh[o1];
            acc[ct] = MFMA(ah0, bh0, acc[ct]);
            acc[ct] = MFMA(ah1, bh1, acc[ct]);
            acc[ct] = MFMA(al0, bh0, acc[ct]);
            acc[ct] = MFMA(al1, bh1, acc[ct]);
        }
        bf16* outb = (bf16*)out;
        #pragma unroll
        for (int ct = 0; ct < 8; ++ct) {
            const int col = wcq * 128 + ct * 16 + l15;
            const float bias = ball2[col];
            #pragma unroll
            for (int r = 0; r < 4; ++r) {
                const int row = rowBase + wr * 16 + quad * 4 + r;
                outb[(size_t)row * D_MODEL + col] = __float2bfloat16(acc[ct][r] + bias);
            }
        }
    }
}

extern "C" void kernel_launch(void* const* d_in, const int* in_sizes, int n_in,
                              void* d_out, int out_size, void* d_ws, size_t ws_size,
                              hipStream_t stream) {
    const void* x  = d_in[0];
    const void* Wq = d_in[1];
    const void* bq = d_in[2];
    const void* Wk = d_in[3];
    const void* bk = d_in[4];
    const void* Wv = d_in[5];
    const void* bv = d_in[6];
    const void* Wo = d_in[7];
    const void* bo = d_in[8];

    const int rows = B_N * S_LEN;                 // 16384
    const int nslots = B_N * NSLOT_B;             // 1088

    char* p = (char*)d_ws;
    int*  flag = (int*)p;                          p += 256;
    bf16* Qb = (bf16*)p;                           p += (size_t)rows * DKV * 2;   // 2 MB
    bf16* Kb = (bf16*)p;                           p += (size_t)rows * DKV * 2;
    bf16* Vt = (bf16*)p;                           p += (size_t)rows * DKV * 2;
    bf16* Wfh = (bf16*)p;                          p += (size_t)12 * 16 * 64 * 8 * 2;  // 196.6 KB
    bf16* Wfl = (bf16*)p;                          p += (size_t)12 * 16 * 64 * 8 * 2;
    float* ball = (float*)p;                       p += 1024;
    bf16* WoFh = (bf16*)p;                         p += (size_t)32 * 2 * 64 * 8 * 2;   // 64 KB
    bf16* WoFl = (bf16*)p;                         p += (size_t)32 * 2 * 64 * 8 * 2;
    float* ball2 = (float*)p;                      p += D_MODEL * 4;
    float* Op = (float*)p;                         p += (size_t)nslots * 128 * DKV * 4; // 34.8 MB
    float2* ML = (float2*)p;                       p += (size_t)nslots * 128 * 8;

    wprep_kernel<<<44, 512, 0, stream>>>(x, Wq, bq, Wk, bk, Wv, bv, Wo, bo,
                                         Wfh, Wfl, ball, WoFh, WoFl, ball2, flag);
    qkv_mfma<<<512, 512, 0, stream>>>(x, Wfh, Wfl, ball, Qb, Kb, Vt, flag);
    attn_mfma<<<nslots, 512, 0, stream>>>(Qb, Kb, Vt, Op, ML);
    proj_mfma<<<512, 512, 0, stream>>>(Op, ML, WoFh, WoFl, ball2, d_out, flag);
}

// Round 17
// 160.650 us; speedup vs baseline: 1.0143x; 1.0143x over previous
//
#include <hip/hip_runtime.h>
#include <hip/hip_bf16.h>

#define S_LEN 4096
#define D_MODEL 512
#define DKV 64
#define B_N 4
#define STR 72    // K-tile LDS row stride (elems)
#define VSTR 136  // V/P LDS row stride (elems), 128 keys + pad

typedef __hip_bfloat16 bf16;
typedef __attribute__((ext_vector_type(8))) short short8;   // 8 bf16 (4 VGPRs)
typedef __attribute__((ext_vector_type(4))) float floatx4;  // MFMA C/D

#define MFMA(a, b, c) __builtin_amdgcn_mfma_f32_16x16x32_bf16(a, b, c, 0, 0, 0)

__device__ __forceinline__ float b2f(bf16 v) { return __bfloat162float(v); }

__device__ __forceinline__ unsigned short f2bits(float v) {
    union { bf16 h; unsigned short u; } cv;
    cv.h = __float2bfloat16(v);
    return cv.u;
}
__device__ __forceinline__ float bits2f(unsigned short u) {
    union { bf16 h; unsigned short u; } cv;
    cv.u = u;
    return b2f(cv.h);
}

// Split-K geometry: tile t (128 rows) has parts(t) = ceil((t+1)/2) parts,
// part p covers K-tiles {2p, min(2p+1, t)}. Slot offset within a batch:
// offT(t) = sum_{m<t} parts(m) = (t^2 + 2t + (t&1)) / 4.  Total 272/batch.
#define NSLOT_B 272
__device__ __forceinline__ int offT(int t) { return (t * t + 2 * t + (t & 1)) >> 2; }

// ---------------------------------------------------------------------------
// Kernel 1a (unified W prep + self-detect): each block detects dtype from x
// (64-lane scan, LDS broadcast); block 0 publishes global flag for qkv/proj.
// Blocks 0..11 -> Wq/Wk/Wv fragment-pack (16 cols each, hi/lo);
// blocks 12..43 -> Wo fragment-pack. Proven layouts from R6.
// ---------------------------------------------------------------------------
__global__ __launch_bounds__(512) void wprep_kernel(
    const void* __restrict__ x,
    const void* __restrict__ Wq, const void* __restrict__ bq,
    const void* __restrict__ Wk, const void* __restrict__ bk,
    const void* __restrict__ Wv, const void* __restrict__ bv,
    const void* __restrict__ Wo, const void* __restrict__ bo,
    bf16* __restrict__ Wfh, bf16* __restrict__ Wfl, float* __restrict__ ball,
    bf16* __restrict__ WoFh, bf16* __restrict__ WoFl, float* __restrict__ ball2,
    int* __restrict__ flag)
{
    __shared__ float xs[16][513];        // [col][k], padded
    __shared__ int sflag;
    const int blk = blockIdx.x;
    const int tid = threadIdx.x;
    union Pack8 { uint4 u; unsigned short s[8]; };

    if (tid < 64) {                      // self-detect (value-based; proven)
        const bf16* xb = (const bf16*)x;
        int bad = 0;
        for (int k = tid; k < 4096; k += 64) {
            float v = fabsf(b2f(xb[2 * k]));
            if (!(v < 64.f)) bad++;
        }
        #pragma unroll
        for (int off = 32; off >= 1; off >>= 1) bad += __shfl_xor(bad, off);
        if (tid == 0) {
            sflag = (bad > 100) ? 1 : 0;
            if (blk == 0) *flag = sflag;
        }
    }
    __syncthreads();
    const int f32 = sflag;

    if (blk < 12) {                      // ---- QKV W prep ----
        const int ct = blk;
        const int c0 = ct * 16;
        const int g = c0 >> 6;           // 0=Q 1=K 2=V
        const int cc0 = c0 & 63;
        const void* W    = (g == 0) ? Wq : (g == 1) ? Wk : Wv;
        const void* bias = (g == 0) ? bq : (g == 1) ? bk : bv;

        #pragma unroll
        for (int i = 0; i < 16; ++i) {
            const int idx = tid + 512 * i;   // 0..8191
            const int d = idx >> 4, j = idx & 15;
            const float v = f32 ? ((const float*)W)[(size_t)d * DKV + cc0 + j]
                                : b2f(((const bf16*)W)[(size_t)d * DKV + cc0 + j]);
            xs[j][d] = v;
        }
        __syncthreads();

        #pragma unroll
        for (int rep = 0; rep < 2; ++rep) {
            const int f = tid + rep * 512;   // fragment id: kt*64 + lane
            const int kt = f >> 6, lane = f & 63;
            const int quad = lane >> 4, l15 = lane & 15;
            Pack8 ph, pl;
            #pragma unroll
            for (int j = 0; j < 8; ++j) {
                const float v = xs[l15][kt * 32 + quad * 8 + j];
                const unsigned short hb = f2bits(v);
                ph.s[j] = hb;
                pl.s[j] = f2bits(v - bits2f(hb));
            }
            const size_t o = (((size_t)ct * 16 + kt) * 64 + lane) * 8;
            *(uint4*)&Wfh[o] = ph.u;
            *(uint4*)&Wfl[o] = pl.u;
        }
        if (tid < 16)
            ball[c0 + tid] = f32 ? ((const float*)bias)[cc0 + tid]
                                 : b2f(((const bf16*)bias)[cc0 + tid]);
    } else {                             // ---- Wo prep ----
        const int ctile = blk - 12;      // 0..31
        const int c0 = ctile * 16;

        #pragma unroll
        for (int rep = 0; rep < 2; ++rep) {
            const int idx = tid + rep * 512; // 0..1023
            const int d = idx >> 4, j = idx & 15;
            const float v = f32 ? ((const float*)Wo)[(size_t)d * D_MODEL + c0 + j]
                                : b2f(((const bf16*)Wo)[(size_t)d * D_MODEL + c0 + j]);
            xs[j][d] = v;
        }
        __syncthreads();

        if (tid < 128) {
            const int kc = tid >> 6, lane = tid & 63;
            const int quad = lane >> 4, l15 = lane & 15;
            Pack8 ph, pl;
            #pragma unroll
            for (int j = 0; j < 8; ++j) {
                const float v = xs[l15][kc * 32 + quad * 8 + j];
                const unsigned short hb = f2bits(v);
                ph.s[j] = hb;
                pl.s[j] = f2bits(v - bits2f(hb));
            }
            const size_t o = (((size_t)ctile * 2 + kc) * 64 + lane) * 8;
            *(uint4*)&WoFh[o] = ph.u;
            *(uint4*)&WoFl[o] = pl.u;
        }
        if (tid < 16)
            ball2[c0 + tid] = f32 ? ((const float*)bo)[c0 + tid]
                                  : b2f(((const bf16*)bo)[c0 + tid]);
    }
}

// ---------------------------------------------------------------------------
// Kernel 1b (unified QKV projection): block-uniform branch on dtype.
// fp32: 3-term hi/lo split; bf16: single term. Proven R8-R14.
// ---------------------------------------------------------------------------
__global__ __launch_bounds__(512) void qkv_mfma(
    const void* __restrict__ x,
    const bf16* __restrict__ Wfh, const bf16* __restrict__ Wfl,
    const float* __restrict__ ball,
    bf16* __restrict__ Qb, bf16* __restrict__ Kb, bf16* __restrict__ Vt,
    const int* __restrict__ flag)
{
    __shared__ unsigned short hiA[32 * D_MODEL];   // 32 KB
    __shared__ unsigned short loA[32 * D_MODEL];   // 32 KB (unused in bf16 path)
    const int tid = threadIdx.x;
    const int rowBase = blockIdx.x * 32;
    const int f32 = *flag;

    union Pack8 { uint4 u; unsigned short s[8]; };
    if (f32) {
        const float* xr = (const float*)x + (size_t)rowBase * D_MODEL;
        #pragma unroll
        for (int i = 0; i < 4; ++i) {
            const int idx = tid + 512 * i;       // 2048 8-elem chunks
            const int r = idx >> 6;
            const int c0 = (idx & 63) << 3;
            const float4 v0 = *(const float4*)&xr[r * D_MODEL + c0];
            const float4 v1 = *(const float4*)&xr[r * D_MODEL + c0 + 4];
            const float vv[8] = {v0.x, v0.y, v0.z, v0.w, v1.x, v1.y, v1.z, v1.w};
            Pack8 ph, pl;
            #pragma unroll
            for (int j = 0; j < 8; ++j) {
                const unsigned short hb = f2bits(vv[j]);
                ph.s[j] = hb;
                pl.s[j] = f2bits(vv[j] - bits2f(hb));
            }
            const int boff = (c0 * 2) ^ ((r & 7) << 4);
            *(uint4*)((char*)hiA + r * 1024 + boff) = ph.u;
            *(uint4*)((char*)loA + r * 1024 + boff) = pl.u;
        }
    } else {
        const unsigned short* xr = (const unsigned short*)x + (size_t)rowBase * D_MODEL;
        #pragma unroll
        for (int i = 0; i < 4; ++i) {
            const int idx = tid + 512 * i;
            const int r = idx >> 6;
            const int c0 = (idx & 63) << 3;
            const uint4 hv = *(const uint4*)&xr[r * D_MODEL + c0];
            const int boff = (c0 * 2) ^ ((r & 7) << 4);
            *(uint4*)((char*)hiA + r * 1024 + boff) = hv;
        }
    }
    __syncthreads();

    const int lane = tid & 63;
    const int w    = tid >> 6;           // 0..7
    const int quad = lane >> 4;
    const int l15  = lane & 15;
    const int wr   = w & 1;              // row half (16 rows)
    const int wq   = w >> 1;             // col quarter (48 cols = 3 tiles)
    const int arow = wr * 16 + l15;
    const char* hib = (const char*)hiA + arow * 1024;
    const char* lob = (const char*)loA + arow * 1024;
    const int swz = (arow & 7) << 4;

    floatx4 acc[3];
    #pragma unroll
    for (int ct = 0; ct < 3; ++ct) acc[ct] = (floatx4){0.f, 0.f, 0.f, 0.f};

    if (f32) {
        for (int kt = 0; kt < 16; ++kt) {
            const int boff = (kt * 64 + quad * 16) ^ swz;
            const short8 ah = *(const short8*)(hib + boff);
            const short8 al = *(const short8*)(lob + boff);
            #pragma unroll
            for (int ct = 0; ct < 3; ++ct) {
                const size_t fo = (((size_t)(wq * 3 + ct) * 16 + kt) * 64 + lane) * 8;
                const short8 bh = *(const short8*)&Wfh[fo];
                const short8 bl = *(const short8*)&Wfl[fo];
                acc[ct] = MFMA(ah, bh, acc[ct]);
                acc[ct] = MFMA(ah, bl, acc[ct]);
                acc[ct] = MFMA(al, bh, acc[ct]);
            }
        }
    } else {
        for (int kt = 0; kt < 16; ++kt) {
            const int boff = (kt * 64 + quad * 16) ^ swz;
            const short8 ah = *(const short8*)(hib + boff);
            #pragma unroll
            for (int ct = 0; ct < 3; ++ct) {
                const size_t fo = (((size_t)(wq * 3 + ct) * 16 + kt) * 64 + lane) * 8;
                const short8 bh = *(const short8*)&Wfh[fo];
                acc[ct] = MFMA(ah, bh, acc[ct]);
            }
        }
    }

    #pragma unroll
    for (int ct = 0; ct < 3; ++ct) {
        const int gc = wq * 48 + ct * 16 + l15;
        const float bias = ball[gc];
        const float scale = (gc < 64) ? 0.18033688f : 1.0f;
        #pragma unroll
        for (int r = 0; r < 4; ++r) {
            const int gr = rowBase + wr * 16 + quad * 4 + r;
            const bf16 o = __float2bfloat16((acc[ct][r] + bias) * scale);
            if (gc < 64)       Qb[(size_t)gr * DKV + gc] = o;
            else if (gc < 128) Kb[(size_t)gr * DKV + (gc - 64)] = o;
            else {
                const int bb = gr >> 12, sidx = gr & (S_LEN - 1);
                Vt[((size_t)bb * DKV + (gc - 128)) * S_LEN + sidx] = o;
            }
        }
    }
}

// ---------------------------------------------------------------------------
// Kernel 2: MFMA flash attention v6 — UNIFORM-WORK split-K (proven R13/R14).
// Q fragments loaded directly from global (L3-hot) — no LDS staging barrier.
// ---------------------------------------------------------------------------
__global__ __launch_bounds__(512, 2) void attn_mfma(
    const bf16* __restrict__ Qg, const bf16* __restrict__ Kg,
    const bf16* __restrict__ Vtg, float* __restrict__ Op,
    float* __restrict__ Mp, float* __restrict__ Lp)
{
    const int bid = blockIdx.x;
    const int b = bid & 3;
    const int j = (NSLOT_B - 1) - (bid >> 2);       // 0..271, big tiles first
    int t = (int)(2.0f * sqrtf((float)j + 1.0f));
    if (t > 31) t = 31;
    while (offT(t) > j) --t;
    while (t < 31 && offT(t + 1) <= j) ++t;
    const int p = j - offT(t);
    const int kb0 = 2 * p;
    const int kb1 = min(2 * p + 1, t);
    const int slot = b * NSLOT_B + offT(t) + p;
    const int rowBase = t * 128;
    const int tid = threadIdx.x;
    const int lane = tid & 63;
    const int w  = tid >> 6;             // wave 0..7: rows w*16..w*16+16
    const int quad = lane >> 4;
    const int l15  = lane & 15;

    __shared__ bf16 Kl[128 * STR];       // [key][dim]     18.0 KB
    __shared__ bf16 Vl[64 * VSTR];       // [vdim][key]    17.0 KB
    __shared__ bf16 Pl[128 * VSTR];      // [row][key]     34.0 KB
    // total 69 KB -> 2 blocks/CU

    const bf16* Qb = Qg + ((size_t)b * S_LEN + rowBase) * DKV;
    const bf16* Kb = Kg + (size_t)b * S_LEN * DKV;
    const bf16* Vb = Vtg + (size_t)b * DKV * S_LEN;

    // Q fragments straight from global (no LDS staging, no barrier)
    short8 qf0, qf1;
    {
        const bf16* qrow = Qb + (size_t)(w * 16 + l15) * DKV + quad * 8;
        qf0 = *(const short8*)qrow;
        qf1 = *(const short8*)(qrow + 32);
    }

    const short s1b = (short)0x3F80;     // bf16 1.0
    const short8 ones = {s1b, s1b, s1b, s1b, s1b, s1b, s1b, s1b};

    floatx4 acc[4];
    #pragma unroll
    for (int v = 0; v < 4; ++v) acc[v] = (floatx4){0.f, 0.f, 0.f, 0.f};
    floatx4 accl = {0.f, 0.f, 0.f, 0.f};
    float m_run[4];
    #pragma unroll
    for (int r = 0; r < 4; ++r) m_run[r] = -1e30f;

    const int kk = tid >> 2, dk = (tid & 3) * 16;   // K staging: 4 thr/row
    const int vd = tid >> 3, vk = (tid & 7) * 16;   // V staging: 8 thr/row

    uint4 kr0, kr1, vr0, vr1;
    {
        const uint4* ks = (const uint4*)&Kb[((size_t)(kb0 * 128 + kk)) * DKV + dk];
        kr0 = ks[0]; kr1 = ks[1];
        const uint4* vs = (const uint4*)&Vb[(size_t)vd * S_LEN + kb0 * 128 + vk];
        vr0 = vs[0]; vr1 = vs[1];
    }

    for (int kb = kb0; kb <= kb1; ++kb) {
        __syncthreads();                 // all waves done reading Kl/Vl
        {
            uint4* kd = (uint4*)&Kl[kk * STR + dk];
            kd[0] = kr0; kd[1] = kr1;
            uint4* vdst = (uint4*)&Vl[vd * VSTR + vk];
            vdst[0] = vr0; vdst[1] = vr1;
        }
        __syncthreads();                 // staging visible
        if (kb + 1 <= kb1) {             // prefetch next tile under compute
            const uint4* ks = (const uint4*)&Kb[((size_t)((kb + 1) * 128 + kk)) * DKV + dk];
            kr0 = ks[0]; kr1 = ks[1];
            const uint4* vs = (const uint4*)&Vb[(size_t)vd * S_LEN + (kb + 1) * 128 + vk];
            vr0 = vs[0]; vr1 = vs[1];
        }

        // S = Q K^T (Q pre-scaled): eight 16x16 key-tiles per wave
        floatx4 s[8];
        #pragma unroll
        for (int jt = 0; jt < 8; ++jt) s[jt] = (floatx4){0.f, 0.f, 0.f, 0.f};
        {
            const int qk = quad * 8;
            #pragma unroll
            for (int jt = 0; jt < 8; ++jt) {
                const int kc = (jt * 16 + l15) * STR + qk;
                const short8 ba = *(const short8*)&Kl[kc];
                const short8 bb = *(const short8*)&Kl[kc + 32];
                s[jt] = MFMA(qf0, ba, s[jt]);
                s[jt] = MFMA(qf1, bb, s[jt]);
            }
        }
        if (kb == t) {                   // causal mask, uniform branch
            const int rowg = rowBase + w * 16 + quad * 4;
            #pragma unroll
            for (int jt = 0; jt < 8; ++jt) {
                const int kg = kb * 128 + jt * 16 + l15;
                #pragma unroll
                for (int r = 0; r < 4; ++r)
                    if (kg > rowg + r) s[jt][r] = -1e30f;
            }
        }
        // wave-private row max: in-thread tree + 16-lane butterfly
        float m4[4];
        #pragma unroll
        for (int r = 0; r < 4; ++r) {
            float mm = s[0][r];
            #pragma unroll
            for (int jt = 1; jt < 8; ++jt) mm = fmaxf(mm, s[jt][r]);
            m4[r] = mm;
        }
        #pragma unroll
        for (int off = 1; off < 16; off <<= 1) {
            #pragma unroll
            for (int r = 0; r < 4; ++r) m4[r] = fmaxf(m4[r], __shfl_xor(m4[r], off));
        }
        float alpha[4];
        #pragma unroll
        for (int r = 0; r < 4; ++r) {
            const float mnew = fmaxf(m_run[r], m4[r]);
            alpha[r] = exp2f(m_run[r] - mnew);   // -1e30 first iter -> 0
            m_run[r] = mnew;
        }
        // P = exp2(S - m); rescale accumulators; write P to wave-private rows
        #pragma unroll
        for (int r = 0; r < 4; ++r) {
            accl[r] *= alpha[r];
            #pragma unroll
            for (int v = 0; v < 4; ++v) acc[v][r] *= alpha[r];
            const int poff = (w * 16 + quad * 4 + r) * VSTR + l15;
            #pragma unroll
            for (int jt = 0; jt < 8; ++jt) {
                const float pp = exp2f(s[jt][r] - m_run[r]);
                Pl[poff + jt * 16] = __float2bfloat16(pp);
            }
        }
        // same-wave LDS RAW: drain writes; "memory" clobber orders the ds_reads
        asm volatile("s_waitcnt lgkmcnt(0)" ::: "memory");

        // O += P V (and l += P . 1 via constant ones B-frag)
        {
            const int pk = quad * 8;
            const int prow = (w * 16 + l15) * VSTR;
            short8 pa[4];
            #pragma unroll
            for (int c = 0; c < 4; ++c)
                pa[c] = *(const short8*)&Pl[prow + pk + c * 32];
            #pragma unroll
            for (int c = 0; c < 4; ++c) accl = MFMA(pa[c], ones, accl);
            #pragma unroll
            for (int v = 0; v < 4; ++v) {
                const int vrow = (v * 16 + l15) * VSTR;
                #pragma unroll
                for (int c = 0; c < 4; ++c) {
                    const short8 vb = *(const short8*)&Vl[vrow + pk + c * 32];
                    acc[v] = MFMA(pa[c], vb, acc[v]);
                }
            }
        }
    }
    // epilogue: store unnormalized O + per-row (m, l) into this part's slot
    #pragma unroll
    for (int r = 0; r < 4; ++r) {
        const int lrow = w * 16 + quad * 4 + r;
        float* op = Op + ((size_t)slot * 128 + lrow) * DKV + l15;
        #pragma unroll
        for (int v = 0; v < 4; ++v) op[v * 16] = acc[v][r];
    }
    if (l15 == 0) {
        #pragma unroll
        for (int r = 0; r < 4; ++r) {
            const int lrow = w * 16 + quad * 4 + r;
            Mp[slot * 128 + lrow] = m_run[r];
            Lp[slot * 128 + lrow] = accl[r];
        }
    }
}

// ---------------------------------------------------------------------------
// Kernel 3 (unified): fused variable-part split-K merge + output projection.
// Merge loop batched 4-wide (independent loads per group). Proven R14.
// ---------------------------------------------------------------------------
#define PSTR 72
__global__ __launch_bounds__(512) void proj_mfma(
    const float* __restrict__ Op, const float* __restrict__ Mp,
    const float* __restrict__ Lp,
    const bf16* __restrict__ WoFh, const bf16* __restrict__ WoFl,
    const float* __restrict__ ball2, void* __restrict__ out,
    const int* __restrict__ flag)
{
    __shared__ unsigned short Ah[32 * PSTR], Al[32 * PSTR];
    const int tid = threadIdx.x;
    const int rowBase = blockIdx.x * 32;
    const int f32 = *flag;

    {   // fused merge: 4 floats per thread (rr = tid>>4, dd = (tid&15)*4)
        const int rr = tid >> 4, dd = (tid & 15) * 4;
        const int row = rowBase + rr;                // global row
        const int bb = row >> 12;
        const int sIdx = row & (S_LEN - 1);
        const int tt = sIdx >> 7;
        const int lrow = sIdx & 127;
        const int nparts = (tt + 2) >> 1;            // ceil((tt+1)/2)
        const int sbase = bb * NSLOT_B + offT(tt);

        float m = -1e30f;
        {
            int i = 0;
            for (; i + 4 <= nparts; i += 4) {
                const float m0 = Mp[(sbase + i + 0) * 128 + lrow];
                const float m1 = Mp[(sbase + i + 1) * 128 + lrow];
                const float m2 = Mp[(sbase + i + 2) * 128 + lrow];
                const float m3 = Mp[(sbase + i + 3) * 128 + lrow];
                m = fmaxf(m, fmaxf(fmaxf(m0, m1), fmaxf(m2, m3)));
            }
            for (; i < nparts; ++i) m = fmaxf(m, Mp[(sbase + i) * 128 + lrow]);
        }
        float denom = 0.f;
        float oacc[4] = {0.f, 0.f, 0.f, 0.f};
        {
            int i = 0;
            for (; i + 4 <= nparts; i += 4) {
                const float m0 = Mp[(sbase + i + 0) * 128 + lrow];
                const float m1 = Mp[(sbase + i + 1) * 128 + lrow];
                const float m2 = Mp[(sbase + i + 2) * 128 + lrow];
                const float m3 = Mp[(sbase + i + 3) * 128 + lrow];
                const float l0 = Lp[(sbase + i + 0) * 128 + lrow];
                const float l1 = Lp[(sbase + i + 1) * 128 + lrow];
                const float l2 = Lp[(sbase + i + 2) * 128 + lrow];
                const float l3 = Lp[(sbase + i + 3) * 128 + lrow];
                const float4 v0 = *(const float4*)&Op[((size_t)(sbase + i + 0) * 128 + lrow) * DKV + dd];
                const float4 v1 = *(const float4*)&Op[((size_t)(sbase + i + 1) * 128 + lrow) * DKV + dd];
                const float4 v2 = *(const float4*)&Op[((size_t)(sbase + i + 2) * 128 + lrow) * DKV + dd];
                const float4 v3 = *(const float4*)&Op[((size_t)(sbase + i + 3) * 128 + lrow) * DKV + dd];
                const float w0 = exp2f(m0 - m), w1 = exp2f(m1 - m);
                const float w2 = exp2f(m2 - m), w3 = exp2f(m3 - m);
                denom += l0 * w0 + l1 * w1 + l2 * w2 + l3 * w3;
                oacc[0] += v0.x * w0 + v1.x * w1 + v2.x * w2 + v3.x * w3;
                oacc[1] += v0.y * w0 + v1.y * w1 + v2.y * w2 + v3.y * w3;
                oacc[2] += v0.z * w0 + v1.z * w1 + v2.z * w2 + v3.z * w3;
                oacc[3] += v0.w * w0 + v1.w * w1 + v2.w * w2 + v3.w * w3;
            }
            for (; i < nparts; ++i) {
                const float wi = exp2f(Mp[(sbase + i) * 128 + lrow] - m);
                denom += Lp[(sbase + i) * 128 + lrow] * wi;
                const float4 v = *(const float4*)&Op[((size_t)(sbase + i) * 128 + lrow) * DKV + dd];
                oacc[0] += v.x * wi; oacc[1] += v.y * wi;
                oacc[2] += v.z * wi; oacc[3] += v.w * wi;
            }
        }
        const float inv = 1.0f / denom;
        union Pack4 { uint2 u; unsigned short s[4]; };
        Pack4 ph, pl;
        #pragma unroll
        for (int jj = 0; jj < 4; ++jj) {
            const float o = oacc[jj] * inv;
            ph.s[jj] = f2bits(o);
            pl.s[jj] = f2bits(o - bits2f(ph.s[jj]));
        }
        *(uint2*)&Ah[rr * PSTR + dd] = ph.u;
        *(uint2*)&Al[rr * PSTR + dd] = pl.u;
    }
    __syncthreads();

    const int lane = tid & 63;
    const int w    = tid >> 6;           // 0..7
    const int quad = lane >> 4;
    const int l15  = lane & 15;
    const int wr   = w & 1;
    const int wcq  = w >> 1;             // 0..3 col quarter (128 cols)

    const int aoff = (wr * 16 + l15) * PSTR + quad * 8;
    const short8 ah0 = *(const short8*)&Ah[aoff];
    const short8 ah1 = *(const short8*)&Ah[aoff + 32];
    const short8 al0 = *(const short8*)&Al[aoff];
    const short8 al1 = *(const short8*)&Al[aoff + 32];

    floatx4 acc[8];
    #pragma unroll
    for (int ct = 0; ct < 8; ++ct) acc[ct] = (floatx4){0.f, 0.f, 0.f, 0.f};

    if (f32) {
        #pragma unroll
        for (int ct = 0; ct < 8; ++ct) {
            const int ctile = wcq * 8 + ct;
            const size_t o0 = (((size_t)ctile * 2 + 0) * 64 + lane) * 8;
            const size_t o1 = (((size_t)ctile * 2 + 1) * 64 + lane) * 8;
            const short8 bh0 = *(const short8*)&WoFh[o0];
            const short8 bh1 = *(const short8*)&WoFh[o1];
            const short8 bl0 = *(const short8*)&WoFl[o0];
            const short8 bl1 = *(const short8*)&WoFl[o1];
            acc[ct] = MFMA(ah0, bh0, acc[ct]);
            acc[ct] = MFMA(ah1, bh1, acc[ct]);
            acc[ct] = MFMA(ah0, bl0, acc[ct]);
            acc[ct] = MFMA(ah1, bl1, acc[ct]);
            acc[ct] = MFMA(al0, bh0, acc[ct]);
            acc[ct] = MFMA(al1, bh1, acc[ct]);
        }
        float* outf = (float*)out;
        #pragma unroll
        for (int ct = 0; ct < 8; ++ct) {
            const int col = wcq * 128 + ct * 16 + l15;
            const float bias = ball2[col];
            #pragma unroll
            for (int r = 0; r < 4; ++r) {
                const int row = rowBase + wr * 16 + quad * 4 + r;
                outf[(size_t)row * D_MODEL + col] = acc[ct][r] + bias;
            }
        }
    } else {
        #pragma unroll
        for (int ct = 0; ct < 8; ++ct) {
            const int ctile = wcq * 8 + ct;
            const size_t o0 = (((size_t)ctile * 2 + 0) * 64 + lane) * 8;
            const size_t o1 = (((size_t)ctile * 2 + 1) * 64 + lane) * 8;
            const short8 bh0 = *(const short8*)&WoFh[o0];
            const short8 bh1 = *(const short8*)&WoFh[o1];
            acc[ct] = MFMA(ah0, bh0, acc[ct]);
            acc[ct] = MFMA(ah1, bh1, acc[ct]);
            acc[ct] = MFMA(al0, bh0, acc[ct]);
            acc[ct] = MFMA(al1, bh1, acc[ct]);
        }
        bf16* outb = (bf16*)out;
        #pragma unroll
        for (int ct = 0; ct < 8; ++ct) {
            const int col = wcq * 128 + ct * 16 + l15;
            const float bias = ball2[col];
            #pragma unroll
            for (int r = 0; r < 4; ++r) {
                const int row = rowBase + wr * 16 + quad * 4 + r;
                outb[(size_t)row * D_MODEL + col] = __float2bfloat16(acc[ct][r] + bias);
            }
        }
    }
}

extern "C" void kernel_launch(void* const* d_in, const int* in_sizes, int n_in,
                              void* d_out, int out_size, void* d_ws, size_t ws_size,
                              hipStream_t stream) {
    const void* x  = d_in[0];
    const void* Wq = d_in[1];
    const void* bq = d_in[2];
    const void* Wk = d_in[3];
    const void* bk = d_in[4];
    const void* Wv = d_in[5];
    const void* bv = d_in[6];
    const void* Wo = d_in[7];
    const void* bo = d_in[8];

    const int rows = B_N * S_LEN;                 // 16384
    const int nslots = B_N * NSLOT_B;             // 1088

    char* p = (char*)d_ws;
    int*  flag = (int*)p;                          p += 256;
    bf16* Qb = (bf16*)p;                           p += (size_t)rows * DKV * 2;   // 2 MB
    bf16* Kb = (bf16*)p;                           p += (size_t)rows * DKV * 2;
    bf16* Vt = (bf16*)p;                           p += (size_t)rows * DKV * 2;
    bf16* Wfh = (bf16*)p;                          p += (size_t)12 * 16 * 64 * 8 * 2;  // 196.6 KB
    bf16* Wfl = (bf16*)p;                          p += (size_t)12 * 16 * 64 * 8 * 2;
    float* ball = (float*)p;                       p += 1024;
    bf16* WoFh = (bf16*)p;                         p += (size_t)32 * 2 * 64 * 8 * 2;   // 64 KB
    bf16* WoFl = (bf16*)p;                         p += (size_t)32 * 2 * 64 * 8 * 2;
    float* ball2 = (float*)p;                      p += D_MODEL * 4;
    float* Op = (float*)p;                         p += (size_t)nslots * 128 * DKV * 4; // 34.8 MB
    float* Mp = (float*)p;                         p += (size_t)nslots * 128 * 4;
    float* Lp = (float*)p;                         p += (size_t)nslots * 128 * 4;

    wprep_kernel<<<44, 512, 0, stream>>>(x, Wq, bq, Wk, bk, Wv, bv, Wo, bo,
                                         Wfh, Wfl, ball, WoFh, WoFl, ball2, flag);
    qkv_mfma<<<512, 512, 0, stream>>>(x, Wfh, Wfl, ball, Qb, Kb, Vt, flag);
    attn_mfma<<<nslots, 512, 0, stream>>>(Qb, Kb, Vt, Op, Mp, Lp);
    proj_mfma<<<512, 512, 0, stream>>>(Op, Mp, Lp, WoFh, WoFl, ball2, d_out, flag);
}